// Round 6
// baseline (451.146 us; speedup 1.0000x reference)
//
#include <hip/hip_runtime.h>
#include <hip/hip_bf16.h>
#include <hip/hip_fp16.h>

#define DIM 512
#define HID 2048
#define NE 8
#define NTOK 4096

typedef _Float16 v8h __attribute__((ext_vector_type(8)));
typedef float v4f __attribute__((ext_vector_type(4)));

__device__ __forceinline__ void load16(const void* g, void* l) {
  __builtin_amdgcn_global_load_lds(
      (const __attribute__((address_space(1))) unsigned int*)g,
      (__attribute__((address_space(3))) unsigned int*)l, 16, 0, 0);
}

// tanh-form GELU: v * sigmoid(1.5957691*v + 0.07135482*v^3), |err| vs erf-GELU ~5e-4
__device__ __forceinline__ float gelu_fast(float v) {
  float v2 = v * v;
  float u = v * __builtin_fmaf(0.07135481627f, v2, 1.5957691216f);
  float t = __expf(-u);
  return v * __builtin_amdgcn_rcpf(1.0f + t);
}

// Fused preamble.
// blocks [0,1024): routing + x->f16 + out bias-init (one wave per token)
// blocks [1024,3072): w1 transpose (fp32 [E][512][2048] -> f16 [E][2048][512]), 64x64 tiles
// blocks [3072,5120): w2 transpose (fp32 [E][2048][512] -> f16 [E][512][2048])
__global__ __launch_bounds__(256) void pre_kernel(const float* __restrict__ x,
                                                  const float* __restrict__ rw,
                                                  const float* __restrict__ rb,
                                                  const float* __restrict__ b2,
                                                  const float* __restrict__ w1,
                                                  const float* __restrict__ w2,
                                                  float* __restrict__ leaf,
                                                  _Float16* __restrict__ xh,
                                                  float* __restrict__ out,
                                                  _Float16* __restrict__ w1t,
                                                  _Float16* __restrict__ w2t) {
  __shared__ float tile[64][65];
  if (blockIdx.x < 1024) {
    const int lane = threadIdx.x & 63;
    const int wave = threadIdx.x >> 6;
    const int n = (blockIdx.x << 2) + wave;
    const float4* xv = (const float4*)(x + (size_t)n * DIM);
    const float4 x0 = xv[lane * 2], x1 = xv[lane * 2 + 1];
    v8h o;
    o[0] = (_Float16)x0.x; o[1] = (_Float16)x0.y; o[2] = (_Float16)x0.z; o[3] = (_Float16)x0.w;
    o[4] = (_Float16)x1.x; o[5] = (_Float16)x1.y; o[6] = (_Float16)x1.z; o[7] = (_Float16)x1.w;
    *(v8h*)(xh + (size_t)n * DIM + lane * 8) = o;
    float logits[7];
#pragma unroll
    for (int rr = 0; rr < 7; ++rr) {
      const float4* wv = (const float4*)(rw + rr * DIM);
      const float4 w0 = wv[lane * 2], w1v = wv[lane * 2 + 1];
      float s = x0.x * w0.x + x0.y * w0.y + x0.z * w0.z + x0.w * w0.w +
                x1.x * w1v.x + x1.y * w1v.y + x1.z * w1v.z + x1.w * w1v.w;
#pragma unroll
      for (int o2 = 32; o2; o2 >>= 1) s += __shfl_xor(s, o2, 64);
      logits[rr] = s + rb[rr];
    }
    const int eidx = lane & 7;
    const float p0 = 1.f / (1.f + __expf(-logits[0]));
    float f = ((eidx >> 2) & 1) ? p0 : 1.f - p0;
    const float p1 = 1.f / (1.f + __expf(-logits[1 + (eidx >> 2)]));
    f *= ((eidx >> 1) & 1) ? p1 : 1.f - p1;
    const float p2 = 1.f / (1.f + __expf(-logits[3 + (eidx >> 1)]));
    f *= (eidx & 1) ? p2 : 1.f - p2;
    if (lane < NE) leaf[(size_t)n * NE + lane] = f;
    float le[NE];
#pragma unroll
    for (int e = 0; e < NE; ++e) le[e] = __shfl(f, e, 64);
    float4 a0 = {0.f, 0.f, 0.f, 0.f}, a1 = {0.f, 0.f, 0.f, 0.f};
#pragma unroll
    for (int e = 0; e < NE; ++e) {
      const float4* bv = (const float4*)(b2 + (size_t)e * DIM + lane * 8);
      const float4 u0 = bv[0], u1 = bv[1];
      a0.x += le[e] * u0.x; a0.y += le[e] * u0.y; a0.z += le[e] * u0.z; a0.w += le[e] * u0.w;
      a1.x += le[e] * u1.x; a1.y += le[e] * u1.y; a1.z += le[e] * u1.z; a1.w += le[e] * u1.w;
    }
    float4* op = (float4*)(out + (size_t)n * DIM + lane * 8);
    op[0] = a0; op[1] = a1;
  } else {
    const float* in;
    _Float16* outp;
    int R, C, rt, ct, e;
    if (blockIdx.x < 3072) {
      const int bx = blockIdx.x - 1024;
      in = w1; outp = w1t; R = DIM; C = HID;
      e = bx >> 8;
      const int rem = bx & 255;       // 8 x 32 tiles
      rt = rem & 7; ct = rem >> 3;
    } else {
      const int bx = blockIdx.x - 3072;
      in = w2; outp = w2t; R = HID; C = DIM;
      e = bx >> 8;
      const int rem = bx & 255;       // 32 x 8 tiles
      rt = rem & 31; ct = rem >> 5;
    }
    const int r0 = rt << 6, c0 = ct << 6;
    const size_t ebase = (size_t)e * R * C;
    const int tid = threadIdx.x;
#pragma unroll
    for (int it = 0; it < 4; ++it) {
      const int s = tid + (it << 8);
      const int row = s >> 4, c4 = (s & 15) << 2;
      const float4 v = *(const float4*)(in + ebase + (size_t)(r0 + row) * C + c0 + c4);
      tile[c4 + 0][row] = v.x;
      tile[c4 + 1][row] = v.y;
      tile[c4 + 2][row] = v.z;
      tile[c4 + 3][row] = v.w;
    }
    __syncthreads();
#pragma unroll
    for (int it = 0; it < 2; ++it) {
      const int s = tid + (it << 8);
      const int oc = s >> 3, seg = s & 7;
      v8h hv;
#pragma unroll
      for (int u = 0; u < 8; ++u) hv[u] = (_Float16)tile[oc][(seg << 3) + u];
      *(v8h*)(outp + ebase + (size_t)(c0 + oc) * R + r0 + (seg << 3)) = hv;
    }
  }
}

// H'[e][n][h] = leaf[n,e] * gelu(X @ W1[e]^T + b1[e])
// 256x256 block, 4 waves of 128x128 (8x8 16x16x32 MFMAs). A via dbuf LDS,
// B direct global->reg (w1t[e] is L2-resident on its XCD). 1 barrier/iter.
__global__ __launch_bounds__(256, 1) void gemm1_kernel(const _Float16* __restrict__ xh,
                                                       const _Float16* __restrict__ w1t,
                                                       const float* __restrict__ b1,
                                                       const float* __restrict__ leaf,
                                                       _Float16* __restrict__ H) {
  const int bx = blockIdx.x;
  const int e = bx & 7;                  // expert == XCD
  const int t = bx >> 3;
  const int mt = t & 15;                 // 16 m-tiles of 256
  const int nt = t >> 4;                 // 8 n-tiles of 256
  const int m0 = mt << 8, n0 = nt << 8;

  __shared__ alignas(16) _Float16 As[2 * 16384];   // 64 KiB, dbuf

  const int tid = threadIdx.x;
  const int lane = tid & 63;
  const int wave = tid >> 6;
  const int wm = wave >> 1, wn = wave & 1;
  const int r = lane & 15, q = lane >> 4;

  // A staging: 2048 chunks of 16B, 8 per thread; XOR-swizzled k-slot
  const int strow = tid >> 3;
  const int c8 = (tid & 7) ^ (strow & 7);
  const _Float16* pa[8];
  _Float16* la[8];
#pragma unroll
  for (int i = 0; i < 8; ++i) {
    pa[i] = xh + (size_t)(m0 + strow + 32 * i) * DIM + (c8 << 3);
    la[i] = As + tid * 8 + i * 2048;
  }
  // A fragment offsets (halves), ks=0; ks=1 is ^32 (verified-conflict-free pattern)
  int aoff[8];
#pragma unroll
  for (int i = 0; i < 8; ++i)
    aoff[i] = (((wm << 7) + (i << 4) + r) << 6) + ((q ^ (r & 7)) << 3);
  // B direct pointers
  const _Float16* pb[8];
#pragma unroll
  for (int j = 0; j < 8; ++j)
    pb[j] = w1t + ((size_t)e * HID + n0 + (wn << 7) + (j << 4) + r) * DIM + (q << 3);

  v4f acc[8][8];
#pragma unroll
  for (int i = 0; i < 8; ++i)
#pragma unroll
    for (int j = 0; j < 8; ++j) acc[i][j] = v4f{0.f, 0.f, 0.f, 0.f};

  // prologue: stage k-tile 0 into buf 0
#pragma unroll
  for (int i = 0; i < 8; ++i) load16(pa[i], la[i]);

#pragma unroll
  for (int kk = 0; kk < 8; ++kk) {
    __syncthreads();                     // drains A-stage for tile kk (issued last iter)
    // B loads for both ks FIRST so their waits don't drain the new A-stage
    v8h b0[8], b1v[8];
#pragma unroll
    for (int j = 0; j < 8; ++j) b0[j] = *(const v8h*)(pb[j] + kk * 64);
#pragma unroll
    for (int j = 0; j < 8; ++j) b1v[j] = *(const v8h*)(pb[j] + kk * 64 + 32);
    if (kk < 7) {
      const int off = (((kk + 1) & 1) << 14);
#pragma unroll
      for (int i = 0; i < 8; ++i) load16(pa[i] + (kk + 1) * 64, la[i] + off);
    }
    const int cp = (kk & 1) << 14;
    v8h a0[8];
#pragma unroll
    for (int i = 0; i < 8; ++i) a0[i] = *(const v8h*)(As + cp + aoff[i]);
#pragma unroll
    for (int i = 0; i < 8; ++i)
#pragma unroll
      for (int j = 0; j < 8; ++j)
        acc[i][j] = __builtin_amdgcn_mfma_f32_16x16x32_f16(a0[i], b0[j], acc[i][j], 0, 0, 0);
#pragma unroll
    for (int i = 0; i < 8; ++i) a0[i] = *(const v8h*)(As + cp + (aoff[i] ^ 32));
#pragma unroll
    for (int i = 0; i < 8; ++i)
#pragma unroll
      for (int j = 0; j < 8; ++j)
        acc[i][j] = __builtin_amdgcn_mfma_f32_16x16x32_f16(a0[i], b1v[j], acc[i][j], 0, 0, 0);
  }

  // epilogue: C/D map col=lane&15, row=q*4+reg
  const float* b1e = b1 + (size_t)e * HID;
  _Float16* He = H + (size_t)e * NTOK * HID;
  float bias[8];
#pragma unroll
  for (int j = 0; j < 8; ++j) bias[j] = b1e[n0 + (wn << 7) + (j << 4) + r];
#pragma unroll
  for (int i = 0; i < 8; ++i) {
    const int rowb = m0 + (wm << 7) + (i << 4) + (q << 2);
#pragma unroll
    for (int rr = 0; rr < 4; ++rr) {
      const int row = rowb + rr;
      const float p = leaf[(size_t)row * NE + e];
      _Float16* hp = He + (size_t)row * HID + n0 + (wn << 7) + r;
#pragma unroll
      for (int j = 0; j < 8; ++j)
        hp[j << 4] = (_Float16)(p * gelu_fast(acc[i][j][rr] + bias[j]));
    }
  }
}

// out += H'[e] @ W2[e]^T (split-K by expert, atomics). Same structure, K=2048.
__global__ __launch_bounds__(256, 1) void gemm2_kernel(const _Float16* __restrict__ H,
                                                       const _Float16* __restrict__ w2t,
                                                       float* __restrict__ out) {
  const int bx = blockIdx.x;
  const int e = bx & 7;                  // expert == XCD; 32 blocks/XCD = 1/CU
  const int t = bx >> 3;
  const int nt = t & 1;                  // 2 d-tiles of 256
  const int mt = t >> 1;                 // 16 m-tiles of 256
  const int m0 = mt << 8, d0 = nt << 8;

  __shared__ alignas(16) _Float16 As[2 * 16384];

  const int tid = threadIdx.x;
  const int lane = tid & 63;
  const int wave = tid >> 6;
  const int wm = wave >> 1, wn = wave & 1;
  const int r = lane & 15, q = lane >> 4;

  const int strow = tid >> 3;
  const int c8 = (tid & 7) ^ (strow & 7);
  const _Float16* pa[8];
  _Float16* la[8];
#pragma unroll
  for (int i = 0; i < 8; ++i) {
    pa[i] = H + ((size_t)e * NTOK + m0 + strow + 32 * i) * HID + (c8 << 3);
    la[i] = As + tid * 8 + i * 2048;
  }
  int aoff[8];
#pragma unroll
  for (int i = 0; i < 8; ++i)
    aoff[i] = (((wm << 7) + (i << 4) + r) << 6) + ((q ^ (r & 7)) << 3);
  const _Float16* pb[8];
#pragma unroll
  for (int j = 0; j < 8; ++j)
    pb[j] = w2t + ((size_t)e * DIM + d0 + (wn << 7) + (j << 4) + r) * HID + (q << 3);

  v4f acc[8][8];
#pragma unroll
  for (int i = 0; i < 8; ++i)
#pragma unroll
    for (int j = 0; j < 8; ++j) acc[i][j] = v4f{0.f, 0.f, 0.f, 0.f};

#pragma unroll
  for (int i = 0; i < 8; ++i) load16(pa[i], la[i]);

  for (int ko = 0; ko < 4; ++ko) {
#pragma unroll
    for (int u = 0; u < 8; ++u) {
      __syncthreads();
      v8h b0[8], b1v[8];
#pragma unroll
      for (int j = 0; j < 8; ++j) b0[j] = *(const v8h*)(pb[j] + u * 64);
#pragma unroll
      for (int j = 0; j < 8; ++j) b1v[j] = *(const v8h*)(pb[j] + u * 64 + 32);
      if (!(ko == 3 && u == 7)) {
        const int off = (((u + 1) & 1) << 14);
#pragma unroll
        for (int i = 0; i < 8; ++i) load16(pa[i] + (u + 1) * 64, la[i] + off);
      }
      const int cp = (u & 1) << 14;
      v8h a0[8];
#pragma unroll
      for (int i = 0; i < 8; ++i) a0[i] = *(const v8h*)(As + cp + aoff[i]);
#pragma unroll
      for (int i = 0; i < 8; ++i)
#pragma unroll
        for (int j = 0; j < 8; ++j)
          acc[i][j] = __builtin_amdgcn_mfma_f32_16x16x32_f16(a0[i], b0[j], acc[i][j], 0, 0, 0);
#pragma unroll
      for (int i = 0; i < 8; ++i) a0[i] = *(const v8h*)(As + cp + (aoff[i] ^ 32));
#pragma unroll
      for (int i = 0; i < 8; ++i)
#pragma unroll
        for (int j = 0; j < 8; ++j)
          acc[i][j] = __builtin_amdgcn_mfma_f32_16x16x32_f16(a0[i], b1v[j], acc[i][j], 0, 0, 0);
    }
#pragma unroll
    for (int i = 0; i < 8; ++i) pa[i] += 512;
#pragma unroll
    for (int j = 0; j < 8; ++j) pb[j] += 512;
  }

#pragma unroll
  for (int i = 0; i < 8; ++i) {
    const int rowb = m0 + (wm << 7) + (i << 4) + (q << 2);
#pragma unroll
    for (int rr = 0; rr < 4; ++rr) {
      float* op = out + (size_t)(rowb + rr) * DIM + d0 + (wn << 7) + r;
#pragma unroll
      for (int j = 0; j < 8; ++j)
        atomicAdd(op + (j << 4), acc[i][j][rr]);
    }
  }
}

extern "C" void kernel_launch(void* const* d_in, const int* in_sizes, int n_in,
                              void* d_out, int out_size, void* d_ws, size_t ws_size,
                              hipStream_t stream) {
  const float* x  = (const float*)d_in[0];
  const float* rw = (const float*)d_in[1];
  const float* rb = (const float*)d_in[2];
  const float* w1 = (const float*)d_in[3];
  const float* b1 = (const float*)d_in[4];
  const float* w2 = (const float*)d_in[5];
  const float* b2 = (const float*)d_in[6];
  float* out = (float*)d_out;

  char* ws = (char*)d_ws;
  const size_t xh_bytes   = (size_t)NTOK * DIM * 2;       // 4 MiB
  const size_t w1t_bytes  = (size_t)NE * HID * DIM * 2;   // 16 MiB
  const size_t w2t_bytes  = (size_t)NE * DIM * HID * 2;   // 16 MiB
  const size_t leaf_bytes = (size_t)NTOK * NE * 4;        // 128 KiB
  const size_t H_bytes    = (size_t)NE * NTOK * HID * 2;  // 128 MiB
  _Float16* xh   = (_Float16*)(ws);
  _Float16* w1t  = (_Float16*)(ws + xh_bytes);
  _Float16* w2t  = (_Float16*)(ws + xh_bytes + w1t_bytes);
  float*    leaf = (float*)(ws + xh_bytes + w1t_bytes + w2t_bytes);
  _Float16* Hbuf = (_Float16*)(ws + xh_bytes + w1t_bytes + w2t_bytes + leaf_bytes);
  if (ws_size < xh_bytes + w1t_bytes + w2t_bytes + leaf_bytes + H_bytes) return;

  pre_kernel<<<5120, 256, 0, stream>>>(x, rw, rb, b2, w1, w2, leaf, xh, out, w1t, w2t);
  gemm1_kernel<<<1024, 256, 0, stream>>>(xh, w1t, b1, leaf, Hbuf);
  gemm2_kernel<<<256, 256, 0, stream>>>(Hbuf, w2t, out);
}

// Round 7
// 346.541 us; speedup vs baseline: 1.3019x; 1.3019x over previous
//
#include <hip/hip_runtime.h>
#include <hip/hip_bf16.h>
#include <hip/hip_fp16.h>

#define DIM 512
#define HID 2048
#define NE 8
#define NTOK 4096

typedef _Float16 v8h __attribute__((ext_vector_type(8)));
typedef float v4f __attribute__((ext_vector_type(4)));

__device__ __forceinline__ void load16(const void* g, void* l) {
  __builtin_amdgcn_global_load_lds(
      (const __attribute__((address_space(1))) unsigned int*)g,
      (__attribute__((address_space(3))) unsigned int*)l, 16, 0, 0);
}

// tanh-form GELU: v * sigmoid(1.5957691*v + 0.07135482*v^3), |err| vs erf-GELU ~5e-4
__device__ __forceinline__ float gelu_fast(float v) {
  float v2 = v * v;
  float u = v * __builtin_fmaf(0.07135481627f, v2, 1.5957691216f);
  float t = __expf(-u);
  return v * __builtin_amdgcn_rcpf(1.0f + t);
}

// Fused preamble.
// blocks [0,1024): routing + x->f16 + out bias-init (one wave per token)
// blocks [1024,3072): w1 transpose (fp32 [E][512][2048] -> f16 [E][2048][512]), 64x64 tiles
// blocks [3072,5120): w2 transpose (fp32 [E][2048][512] -> f16 [E][512][2048])
__global__ __launch_bounds__(256) void pre_kernel(const float* __restrict__ x,
                                                  const float* __restrict__ rw,
                                                  const float* __restrict__ rb,
                                                  const float* __restrict__ b2,
                                                  const float* __restrict__ w1,
                                                  const float* __restrict__ w2,
                                                  float* __restrict__ leaf,
                                                  _Float16* __restrict__ xh,
                                                  float* __restrict__ out,
                                                  _Float16* __restrict__ w1t,
                                                  _Float16* __restrict__ w2t) {
  __shared__ float tile[64][65];
  if (blockIdx.x < 1024) {
    const int lane = threadIdx.x & 63;
    const int wave = threadIdx.x >> 6;
    const int n = (blockIdx.x << 2) + wave;
    const float4* xv = (const float4*)(x + (size_t)n * DIM);
    const float4 x0 = xv[lane * 2], x1 = xv[lane * 2 + 1];
    v8h o;
    o[0] = (_Float16)x0.x; o[1] = (_Float16)x0.y; o[2] = (_Float16)x0.z; o[3] = (_Float16)x0.w;
    o[4] = (_Float16)x1.x; o[5] = (_Float16)x1.y; o[6] = (_Float16)x1.z; o[7] = (_Float16)x1.w;
    *(v8h*)(xh + (size_t)n * DIM + lane * 8) = o;
    float logits[7];
#pragma unroll
    for (int rr = 0; rr < 7; ++rr) {
      const float4* wv = (const float4*)(rw + rr * DIM);
      const float4 w0 = wv[lane * 2], w1v = wv[lane * 2 + 1];
      float s = x0.x * w0.x + x0.y * w0.y + x0.z * w0.z + x0.w * w0.w +
                x1.x * w1v.x + x1.y * w1v.y + x1.z * w1v.z + x1.w * w1v.w;
#pragma unroll
      for (int o2 = 32; o2; o2 >>= 1) s += __shfl_xor(s, o2, 64);
      logits[rr] = s + rb[rr];
    }
    const int eidx = lane & 7;
    const float p0 = 1.f / (1.f + __expf(-logits[0]));
    float f = ((eidx >> 2) & 1) ? p0 : 1.f - p0;
    const float p1 = 1.f / (1.f + __expf(-logits[1 + (eidx >> 2)]));
    f *= ((eidx >> 1) & 1) ? p1 : 1.f - p1;
    const float p2 = 1.f / (1.f + __expf(-logits[3 + (eidx >> 1)]));
    f *= (eidx & 1) ? p2 : 1.f - p2;
    if (lane < NE) leaf[(size_t)n * NE + lane] = f;
    float le[NE];
#pragma unroll
    for (int e = 0; e < NE; ++e) le[e] = __shfl(f, e, 64);
    float4 a0 = {0.f, 0.f, 0.f, 0.f}, a1 = {0.f, 0.f, 0.f, 0.f};
#pragma unroll
    for (int e = 0; e < NE; ++e) {
      const float4* bv = (const float4*)(b2 + (size_t)e * DIM + lane * 8);
      const float4 u0 = bv[0], u1 = bv[1];
      a0.x += le[e] * u0.x; a0.y += le[e] * u0.y; a0.z += le[e] * u0.z; a0.w += le[e] * u0.w;
      a1.x += le[e] * u1.x; a1.y += le[e] * u1.y; a1.z += le[e] * u1.z; a1.w += le[e] * u1.w;
    }
    float4* op = (float4*)(out + (size_t)n * DIM + lane * 8);
    op[0] = a0; op[1] = a1;
  } else {
    const float* in;
    _Float16* outp;
    int R, C, rt, ct, e;
    if (blockIdx.x < 3072) {
      const int bx = blockIdx.x - 1024;
      in = w1; outp = w1t; R = DIM; C = HID;
      e = bx >> 8;
      const int rem = bx & 255;       // 8 x 32 tiles
      rt = rem & 7; ct = rem >> 3;
    } else {
      const int bx = blockIdx.x - 3072;
      in = w2; outp = w2t; R = HID; C = DIM;
      e = bx >> 8;
      const int rem = bx & 255;       // 32 x 8 tiles
      rt = rem & 31; ct = rem >> 5;
    }
    const int r0 = rt << 6, c0 = ct << 6;
    const size_t ebase = (size_t)e * R * C;
    const int tid = threadIdx.x;
#pragma unroll
    for (int it = 0; it < 4; ++it) {
      const int s = tid + (it << 8);
      const int row = s >> 4, c4 = (s & 15) << 2;
      const float4 v = *(const float4*)(in + ebase + (size_t)(r0 + row) * C + c0 + c4);
      tile[c4 + 0][row] = v.x;
      tile[c4 + 1][row] = v.y;
      tile[c4 + 2][row] = v.z;
      tile[c4 + 3][row] = v.w;
    }
    __syncthreads();
#pragma unroll
    for (int it = 0; it < 2; ++it) {
      const int s = tid + (it << 8);
      const int oc = s >> 3, seg = s & 7;
      v8h hv;
#pragma unroll
      for (int u = 0; u < 8; ++u) hv[u] = (_Float16)tile[oc][(seg << 3) + u];
      *(v8h*)(outp + ebase + (size_t)(c0 + oc) * R + r0 + (seg << 3)) = hv;
    }
  }
}

// H'[e][n][h] = leaf[n,e] * gelu(X @ W1[e]^T + b1[e])
// 128x128 block, 2 waves of 128x64 (8x4 16x16x32 MFMA, 128 acc VGPRs).
// A (tokens) staged in 16KB LDS; B (weights) direct global->reg (L2-resident/XCD).
__global__ __launch_bounds__(128, 2) void gemm1_kernel(const _Float16* __restrict__ xh,
                                                       const _Float16* __restrict__ w1t,
                                                       const float* __restrict__ b1,
                                                       const float* __restrict__ leaf,
                                                       _Float16* __restrict__ H) {
  const int bx = blockIdx.x;
  const int e = bx & 7;                  // expert == XCD: w1t[e] (2MB) L2-resident
  const int t = bx >> 3;
  const int mt = t & 31;                 // 32 m-tiles of 128
  const int nt = t >> 5;                 // 16 n-tiles of 128
  const int m0 = mt << 7, n0 = nt << 7;

  __shared__ alignas(16) _Float16 As[128 * 64];   // 16 KiB

  const int tid = threadIdx.x;           // 0..127
  const int lane = tid & 63;
  const int wn = tid >> 6;               // wave = column half
  const int r = lane & 15, q = lane >> 4;

  // A staging: 1024 chunks of 16B, 8/thread; XOR-swizzled k-slot (verified conflict-free)
  const int strow = tid >> 3;            // 0..15
  const int c8 = (tid & 7) ^ (strow & 7);
  const _Float16* pa[8];
  _Float16* la[8];
#pragma unroll
  for (int i = 0; i < 8; ++i) {
    pa[i] = xh + (size_t)(m0 + strow + 16 * i) * DIM + (c8 << 3);
    la[i] = As + tid * 8 + i * 1024;
  }
  // A fragment: one base, row-stride 16*64 halves folds to ds_read imm offset
  const int abase = (r << 6) + ((q ^ (r & 7)) << 3);
  // B direct pointers (4 n-tiles for this wave)
  const _Float16* pb[4];
#pragma unroll
  for (int j = 0; j < 4; ++j)
    pb[j] = w1t + ((size_t)e * HID + n0 + (wn << 6) + (j << 4) + r) * DIM + (q << 3);

  v4f acc[8][4];
#pragma unroll
  for (int i = 0; i < 8; ++i)
#pragma unroll
    for (int j = 0; j < 4; ++j) acc[i][j] = v4f{0.f, 0.f, 0.f, 0.f};

#pragma unroll
  for (int kk = 0; kk < 8; ++kk) {       // K=512, BK=64; kk*128B folds to imm
    // B loads first so their waits never drain the A stage
    v8h bv0[4], bv1[4];
#pragma unroll
    for (int j = 0; j < 4; ++j) bv0[j] = *(const v8h*)(pb[j] + kk * 64);
#pragma unroll
    for (int j = 0; j < 4; ++j) bv1[j] = *(const v8h*)(pb[j] + kk * 64 + 32);
#pragma unroll
    for (int i = 0; i < 8; ++i) load16(pa[i] + kk * 64, la[i]);
    __syncthreads();
    v8h a[8];
#pragma unroll
    for (int i = 0; i < 8; ++i) a[i] = *(const v8h*)(As + abase + i * 1024);
#pragma unroll
    for (int i = 0; i < 8; ++i)
#pragma unroll
      for (int j = 0; j < 4; ++j)
        acc[i][j] = __builtin_amdgcn_mfma_f32_16x16x32_f16(a[i], bv0[j], acc[i][j], 0, 0, 0);
#pragma unroll
    for (int i = 0; i < 8; ++i) a[i] = *(const v8h*)(As + (abase ^ 32) + i * 1024);
#pragma unroll
    for (int i = 0; i < 8; ++i)
#pragma unroll
      for (int j = 0; j < 4; ++j)
        acc[i][j] = __builtin_amdgcn_mfma_f32_16x16x32_f16(a[i], bv1[j], acc[i][j], 0, 0, 0);
    __syncthreads();
  }

  // epilogue: C/D map col=lane&15, row=q*4+reg
  const float* b1e = b1 + (size_t)e * HID;
  _Float16* He = H + (size_t)e * NTOK * HID;
  float bias[4];
#pragma unroll
  for (int j = 0; j < 4; ++j) bias[j] = b1e[n0 + (wn << 6) + (j << 4) + r];
#pragma unroll
  for (int i = 0; i < 8; ++i) {
    const int rowb = m0 + (i << 4) + (q << 2);
#pragma unroll
    for (int rr = 0; rr < 4; ++rr) {
      const int row = rowb + rr;
      const float p = leaf[(size_t)row * NE + e];
      _Float16* hp = He + (size_t)row * HID + n0 + (wn << 6) + r;
#pragma unroll
      for (int j = 0; j < 4; ++j)
        hp[j << 4] = (_Float16)(p * gelu_fast(acc[i][j][rr] + bias[j]));
    }
  }
}

// out += H'[e] @ W2[e]^T (split-K by expert, atomics). Same structure, K=2048.
__global__ __launch_bounds__(128, 2) void gemm2_kernel(const _Float16* __restrict__ H,
                                                       const _Float16* __restrict__ w2t,
                                                       float* __restrict__ out) {
  const int bx = blockIdx.x;
  const int e = bx & 7;                  // expert == XCD: w2t[e] (2MB) L2-resident
  const int t = bx >> 3;                 // 0..127
  const int dt = t & 3;                  // dt fastest: d-blocks of an m-slice co-resident
  const int mt = t >> 2;                 // 32 m-tiles of 128
  const int m0 = mt << 7, d0 = dt << 7;

  __shared__ alignas(16) _Float16 As[128 * 64];

  const int tid = threadIdx.x;
  const int lane = tid & 63;
  const int wn = tid >> 6;
  const int r = lane & 15, q = lane >> 4;

  const int strow = tid >> 3;
  const int c8 = (tid & 7) ^ (strow & 7);
  const _Float16* pa[8];
  _Float16* la[8];
#pragma unroll
  for (int i = 0; i < 8; ++i) {
    pa[i] = H + ((size_t)e * NTOK + m0 + strow + 16 * i) * HID + (c8 << 3);
    la[i] = As + tid * 8 + i * 1024;
  }
  const int abase = (r << 6) + ((q ^ (r & 7)) << 3);
  const _Float16* pb[4];
#pragma unroll
  for (int j = 0; j < 4; ++j)
    pb[j] = w2t + ((size_t)e * DIM + d0 + (wn << 6) + (j << 4) + r) * HID + (q << 3);

  v4f acc[8][4];
#pragma unroll
  for (int i = 0; i < 8; ++i)
#pragma unroll
    for (int j = 0; j < 4; ++j) acc[i][j] = v4f{0.f, 0.f, 0.f, 0.f};

  for (int ko = 0; ko < 4; ++ko) {       // K=2048 = 4 x (8 unrolled BK=64 iters)
#pragma unroll
    for (int u = 0; u < 8; ++u) {
      v8h bv0[4], bv1[4];
#pragma unroll
      for (int j = 0; j < 4; ++j) bv0[j] = *(const v8h*)(pb[j] + u * 64);
#pragma unroll
      for (int j = 0; j < 4; ++j) bv1[j] = *(const v8h*)(pb[j] + u * 64 + 32);
#pragma unroll
      for (int i = 0; i < 8; ++i) load16(pa[i] + u * 64, la[i]);
      __syncthreads();
      v8h a[8];
#pragma unroll
      for (int i = 0; i < 8; ++i) a[i] = *(const v8h*)(As + abase + i * 1024);
#pragma unroll
      for (int i = 0; i < 8; ++i)
#pragma unroll
        for (int j = 0; j < 4; ++j)
          acc[i][j] = __builtin_amdgcn_mfma_f32_16x16x32_f16(a[i], bv0[j], acc[i][j], 0, 0, 0);
#pragma unroll
      for (int i = 0; i < 8; ++i) a[i] = *(const v8h*)(As + (abase ^ 32) + i * 1024);
#pragma unroll
      for (int i = 0; i < 8; ++i)
#pragma unroll
        for (int j = 0; j < 4; ++j)
          acc[i][j] = __builtin_amdgcn_mfma_f32_16x16x32_f16(a[i], bv1[j], acc[i][j], 0, 0, 0);
      __syncthreads();
    }
#pragma unroll
    for (int i = 0; i < 8; ++i) pa[i] += 512;
#pragma unroll
    for (int j = 0; j < 4; ++j) pb[j] += 512;
  }

#pragma unroll
  for (int i = 0; i < 8; ++i) {
    const int rowb = m0 + (i << 4) + (q << 2);
#pragma unroll
    for (int rr = 0; rr < 4; ++rr) {
      float* op = out + (size_t)(rowb + rr) * DIM + d0 + (wn << 6) + r;
#pragma unroll
      for (int j = 0; j < 4; ++j)
        atomicAdd(op + (j << 4), acc[i][j][rr]);
    }
  }
}

extern "C" void kernel_launch(void* const* d_in, const int* in_sizes, int n_in,
                              void* d_out, int out_size, void* d_ws, size_t ws_size,
                              hipStream_t stream) {
  const float* x  = (const float*)d_in[0];
  const float* rw = (const float*)d_in[1];
  const float* rb = (const float*)d_in[2];
  const float* w1 = (const float*)d_in[3];
  const float* b1 = (const float*)d_in[4];
  const float* w2 = (const float*)d_in[5];
  const float* b2 = (const float*)d_in[6];
  float* out = (float*)d_out;

  char* ws = (char*)d_ws;
  const size_t xh_bytes   = (size_t)NTOK * DIM * 2;       // 4 MiB
  const size_t w1t_bytes  = (size_t)NE * HID * DIM * 2;   // 16 MiB
  const size_t w2t_bytes  = (size_t)NE * DIM * HID * 2;   // 16 MiB
  const size_t leaf_bytes = (size_t)NTOK * NE * 4;        // 128 KiB
  const size_t H_bytes    = (size_t)NE * NTOK * HID * 2;  // 128 MiB
  _Float16* xh   = (_Float16*)(ws);
  _Float16* w1t  = (_Float16*)(ws + xh_bytes);
  _Float16* w2t  = (_Float16*)(ws + xh_bytes + w1t_bytes);
  float*    leaf = (float*)(ws + xh_bytes + w1t_bytes + w2t_bytes);
  _Float16* Hbuf = (_Float16*)(ws + xh_bytes + w1t_bytes + w2t_bytes + leaf_bytes);
  if (ws_size < xh_bytes + w1t_bytes + w2t_bytes + leaf_bytes + H_bytes) return;

  pre_kernel<<<5120, 256, 0, stream>>>(x, rw, rb, b2, w1, w2, leaf, xh, out, w1t, w2t);
  gemm1_kernel<<<4096, 128, 0, stream>>>(xh, w1t, b1, leaf, Hbuf);
  gemm2_kernel<<<1024, 128, 0, stream>>>(Hbuf, w2t, out);
}